// Round 9
// baseline (212.764 us; speedup 1.0000x reference)
//
#include <hip/hip_runtime.h>
#include <hip/hip_bf16.h>

// B=4, S=2048, D=1024, H=16, HD=64, causal MHA forward, fp32 in/out.
// Pipeline: 3 proj GEMMs (fp32 in, fused bf16 convert) -> flash attn -> out GEMM.

#define SLEN 2048
#define DMOD 1024

typedef __attribute__((ext_vector_type(8))) short s16x8;   // 8 bf16 (4 VGPRs)
typedef __attribute__((ext_vector_type(4))) float f32x4;

__device__ __forceinline__ unsigned short f2bf(float f) {
    union { __hip_bfloat16 h; unsigned short u; } cv;
    cv.h = __float2bfloat16(f);
    return cv.u;
}
// packed bf16 pair via HW instruction: low16 <- a, high16 <- b (RNE)
__device__ __forceinline__ unsigned cvtpk(float a, float b) {
    unsigned r;
    asm("v_cvt_pk_bf16_f32 %0, %1, %2" : "=v"(r) : "v"(a), "v"(b));
    return r;
}

// async global->LDS, 16B per lane; LDS dest is wave-uniform base + lane*16
__device__ __forceinline__ void gload_lds16(const void* g, void* l) {
    __builtin_amdgcn_global_load_lds(
        (const __attribute__((address_space(1))) void*)g,
        (__attribute__((address_space(3))) void*)l, 16, 0, 0);
}

// ---------------- GEMM v4: Y = A @ W^T + bias, fused fp32->bf16 staging ----
// A: [8192,1024] fp32 (ABF=false) or bf16 (ABF=true). W: [1024,1024] fp32.
// 128x128 tile, BK=64, 4 waves, double-buffered bf16 LDS.
// T14 schedule per K-step: {issue loads t+1} -> {MFMA t} -> {cvt+ds_write t+1}
// -> one barrier. Global latency hides under the MFMA phase; barrier drains
// only LDS writes (vmcnt consumed by cvtpk beforehand).
// MODE 0: bf16 out [B,H,S,HD]  MODE 1: bf16 out [B,H,HD,S]  MODE 2: fp32 [B,S,D]
template<int MODE, bool ABF>
__global__ __launch_bounds__(256, 2) void gemm_v4(
    const void* __restrict__ Aptr, const float* __restrict__ Wp,
    const float* __restrict__ bias, void* __restrict__ outp)
{
    __shared__ unsigned short Asm[2][8192];   // 16 KB per buffer, swizzled
    __shared__ unsigned short Bsm[2][8192];

    const int tid  = threadIdx.x;
    const int lane = tid & 63, wid = tid >> 6;
    const int l15 = lane & 15, lhi = lane >> 4;

    // XCD swizzle: 512 blocks, each XCD gets 8 consecutive m-panels (all n).
    const int flat = blockIdx.x;
    const int logical = (flat & 7) * 64 + (flat >> 3);
    const int m0 = (logical >> 3) * 128, n0 = (logical & 7) * 128;
    const int wr = wid >> 1, wc = wid & 1;

    // staging geometry: 4 chunks/thread, each = one 8-el granule of one row
    int srow[4], sg[4], soff[4];
#pragma unroll
    for (int i = 0; i < 4; ++i) {
        const int f = i * 256 + tid;
        srow[i] = f >> 3;
        sg[i]   = f & 7;
        soff[i] = srow[i] * 128 + ((sg[i] ^ (srow[i] & 7)) * 16);  // swizzled byte off
    }

    // frag read byte offsets (same swizzle)
    int aoff[2][4], boff[2][4];
#pragma unroll
    for (int kk = 0; kk < 2; ++kk)
#pragma unroll
        for (int i = 0; i < 4; ++i) {
            const int s = ((4 * kk + lhi) ^ (l15 & 7)) * 16;
            aoff[kk][i] = (wr * 64 + i * 16 + l15) * 128 + s;
            boff[kk][i] = (wc * 64 + i * 16 + l15) * 128 + s;
        }

    f32x4 acc[4][4];
#pragma unroll
    for (int i = 0; i < 4; ++i)
#pragma unroll
        for (int j = 0; j < 4; ++j) acc[i][j] = (f32x4)0.f;

    // in-flight staging registers
    float4 aw[8], ww[8];
    int4 ab[4];

    auto loadS = [&](int k0) {
        if constexpr (ABF) {
            const unsigned short* Af = (const unsigned short*)Aptr;
#pragma unroll
            for (int i = 0; i < 4; ++i)
                ab[i] = *reinterpret_cast<const int4*>(
                    &Af[(size_t)(m0 + srow[i]) * 1024 + k0 + sg[i] * 8]);
        } else {
            const float* Af = (const float*)Aptr;
#pragma unroll
            for (int i = 0; i < 4; ++i) {
                const float* s = &Af[(size_t)(m0 + srow[i]) * 1024 + k0 + sg[i] * 8];
                aw[2 * i]     = *reinterpret_cast<const float4*>(s);
                aw[2 * i + 1] = *reinterpret_cast<const float4*>(s + 4);
            }
        }
#pragma unroll
        for (int i = 0; i < 4; ++i) {
            const float* s = &Wp[(size_t)(n0 + srow[i]) * 1024 + k0 + sg[i] * 8];
            ww[2 * i]     = *reinterpret_cast<const float4*>(s);
            ww[2 * i + 1] = *reinterpret_cast<const float4*>(s + 4);
        }
    };

    auto writeS = [&](int bsel) {
#pragma unroll
        for (int i = 0; i < 4; ++i) {
            if constexpr (ABF) {
                *reinterpret_cast<int4*>((char*)&Asm[bsel][0] + soff[i]) = ab[i];
            } else {
                uint4 u;
                u.x = cvtpk(aw[2 * i].x,     aw[2 * i].y);
                u.y = cvtpk(aw[2 * i].z,     aw[2 * i].w);
                u.z = cvtpk(aw[2 * i + 1].x, aw[2 * i + 1].y);
                u.w = cvtpk(aw[2 * i + 1].z, aw[2 * i + 1].w);
                *reinterpret_cast<uint4*>((char*)&Asm[bsel][0] + soff[i]) = u;
            }
            uint4 w;
            w.x = cvtpk(ww[2 * i].x,     ww[2 * i].y);
            w.y = cvtpk(ww[2 * i].z,     ww[2 * i].w);
            w.z = cvtpk(ww[2 * i + 1].x, ww[2 * i + 1].y);
            w.w = cvtpk(ww[2 * i + 1].z, ww[2 * i + 1].w);
            *reinterpret_cast<uint4*>((char*)&Bsm[bsel][0] + soff[i]) = w;
        }
    };

    loadS(0);
    writeS(0);
    __syncthreads();

#pragma unroll 1
    for (int kt = 0; kt < 16; ++kt) {
        if (kt < 15) loadS((kt + 1) * 64);    // issue early: hides under MFMAs
        const char* AB = (const char*)&Asm[kt & 1][0];
        const char* BB = (const char*)&Bsm[kt & 1][0];
#pragma unroll
        for (int kk = 0; kk < 2; ++kk) {
            s16x8 af[4], bfv[4];
#pragma unroll
            for (int i = 0; i < 4; ++i) af[i]  = *reinterpret_cast<const s16x8*>(AB + aoff[kk][i]);
#pragma unroll
            for (int j = 0; j < 4; ++j) bfv[j] = *reinterpret_cast<const s16x8*>(BB + boff[kk][j]);
#pragma unroll
            for (int i = 0; i < 4; ++i)
#pragma unroll
                for (int j = 0; j < 4; ++j)
                    acc[i][j] = __builtin_amdgcn_mfma_f32_16x16x32_bf16(af[i], bfv[j], acc[i][j], 0, 0, 0);
        }
        if (kt < 15) writeS((kt + 1) & 1);    // cvt+write late (T14 split)
        __syncthreads();                      // drains LDS writes only
    }

    // epilogue: C/D layout col=lane&15, row=(lane>>4)*4+reg
#pragma unroll
    for (int j = 0; j < 4; ++j) {
        const int col = n0 + wc * 64 + j * 16 + l15;
        const float bv = bias[col];
#pragma unroll
        for (int i = 0; i < 4; ++i) {
#pragma unroll
            for (int r = 0; r < 4; ++r) {
                const int row = m0 + wr * 64 + i * 16 + lhi * 4 + r;
                const float val = acc[i][j][r] + bv;
                if constexpr (MODE == 2) {
                    ((float*)outp)[(size_t)row * 1024 + col] = val;
                } else if constexpr (MODE == 0) {
                    ((unsigned short*)outp)[(size_t)((row >> 11) * 16 + (col >> 6)) * 131072
                                            + (size_t)(row & 2047) * 64 + (col & 63)] = f2bf(val);
                } else {
                    ((unsigned short*)outp)[(size_t)((row >> 11) * 16 + (col >> 6)) * 131072
                                            + (size_t)(col & 63) * 2048 + (row & 2047)] = f2bf(val);
                }
            }
        }
    }
}

// ---------------- flash attention v7 (unchanged from round 8) ----------------
#define EXPC 0.18033688011112043f   // 0.125 * log2(e)

__global__ __launch_bounds__(256, 4) void attn_kernel(
    const unsigned short* __restrict__ Q,
    const unsigned short* __restrict__ Kc,
    const unsigned short* __restrict__ Vt,
    unsigned short* __restrict__ Ao)
{
    __shared__ unsigned short Kbuf[2][4096];   // [64 kv][64 d] swizzled
    __shared__ unsigned short Vbuf[2][4096];   // [64 d][64 kv] swizzled
    __shared__ unsigned short Psm[4][1024];    // per-wave [16 q][64 kv] swizzled

    const int tid = threadIdx.x, lane = tid & 63, wid = tid >> 6;
    const int l15 = lane & 15, lhi = lane >> 4;
    const int sK = l15 & 7;
    const int sub = lane >> 3, c8s = lane & 7;
    const int thr = wid * 16 + l15;            // causal threshold (q0 cancels)

    int ko[8], pr[2], pw[4];
#pragma unroll
    for (int kk = 0; kk < 2; ++kk) {
        pr[kk] = (l15 * 8 + ((4 * kk + lhi) ^ sK)) * 16;
#pragma unroll
        for (int nb = 0; nb < 4; ++nb)
            ko[kk * 4 + nb] = ((nb * 16 + l15) * 8 + ((4 * kk + lhi) ^ sK)) * 16;
    }
#pragma unroll
    for (int nb = 0; nb < 4; ++nb)
        pw[nb] = (l15 * 16 + ((nb * 4 + lhi) ^ (2 * sK))) * 8;

    const int flat = blockIdx.x;
    const int logical = (flat & 7) * 128 + (flat >> 3);
    const int bx = logical & 15, bh = logical >> 4;

    const size_t base = (size_t)bh * SLEN * 64;
    const unsigned short* Qb = Q + base;
    const unsigned short* Kb = Kc + base;
    const unsigned short* Vb = Vt + base;      // [64][SLEN]
    const int b = bh >> 4, h = bh & 15;
    const int scol = (c8s ^ sub) * 8;

    const f32x4 fzero = (f32x4)0.f;
    const s16x8 onesb = (s16x8)(short)0x3F80;  // bf16 1.0 splat (l-sum B)

#pragma unroll 1
    for (int seg = 0; seg < 2; ++seg) {
        const int qt = seg ? (31 - bx) : bx;
        const int q0 = qt * 64;

        s16x8 aq[2];
#pragma unroll
        for (int kk = 0; kk < 2; ++kk)
            aq[kk] = *reinterpret_cast<const s16x8*>(
                &Qb[(size_t)(q0 + wid * 16 + l15) * 64 + kk * 32 + 8 * lhi]);

        f32x4 o_acc[4];
#pragma unroll
        for (int nb = 0; nb < 4; ++nb) o_acc[nb] = (f32x4)0.f;
        f32x4 l_acc = (f32x4)0.f;
        float m_r = -1e30f;

        const unsigned short* kpt = Kb + (16 * wid + sub) * 64 + scol;
        const unsigned short* vpt = Vb + (size_t)(16 * wid + sub) * SLEN + scol;

        auto stage = [&](int bsel) {
            char* kd = (char*)Kbuf + bsel * 8192 + wid * 2048;
            char* vd = (char*)Vbuf + bsel * 8192 + wid * 2048;
            gload_lds16(kpt,         kd);
            gload_lds16(kpt + 512,   kd + 1024);
            gload_lds16(vpt,         vd);
            gload_lds16(vpt + 16384, vd + 1024);
            kpt += 4096; vpt += 64;
        };

        auto tile = [&](int cbo, bool domask) {
            const char* KB = (const char*)Kbuf + cbo;
            const char* VB = (const char*)Vbuf + cbo;
            char* PW = (char*)Psm + wid * 2048;

            f32x4 sc2[4];
            __builtin_amdgcn_s_setprio(1);
#pragma unroll
            for (int kk = 0; kk < 2; ++kk) {
                s16x8 ak[4];
#pragma unroll
                for (int nb = 0; nb < 4; ++nb)
                    ak[nb] = *reinterpret_cast<const s16x8*>(KB + ko[kk * 4 + nb]);
#pragma unroll
                for (int nb = 0; nb < 4; ++nb)
                    sc2[nb] = __builtin_amdgcn_mfma_f32_16x16x32_bf16(
                        ak[nb], aq[kk], kk == 0 ? fzero : sc2[nb], 0, 0, 0);
            }
            __builtin_amdgcn_s_setprio(0);

            if (domask) {
#pragma unroll
                for (int nb = 0; nb < 4; ++nb)
#pragma unroll
                    for (int r = 0; r < 4; ++r)
                        if (nb * 16 + lhi * 4 + r > thr) sc2[nb][r] = -3e30f;
            }
            float tm[4];
#pragma unroll
            for (int nb = 0; nb < 4; ++nb)
                tm[nb] = fmaxf(fmaxf(sc2[nb][0], sc2[nb][1]),
                               fmaxf(sc2[nb][2], sc2[nb][3]));
            float tmx = fmaxf(fmaxf(tm[0], tm[1]), fmaxf(tm[2], tm[3]));

            if (__any(tmx - m_r > 64.0f)) {      // rare rescale
                float tf = fmaxf(tmx, __shfl_xor(tmx, 16));
                tf = fmaxf(tf, __shfl_xor(tf, 32));
                const float mn = fmaxf(m_r, tf);
                const float alpha = exp2f((m_r - mn) * EXPC);
                m_r = mn;
                float ar[4];
#pragma unroll
                for (int r = 0; r < 4; ++r) ar[r] = __shfl(alpha, lhi * 4 + r);
#pragma unroll
                for (int r = 0; r < 4; ++r) l_acc[r] *= ar[r];
#pragma unroll
                for (int nb = 0; nb < 4; ++nb)
#pragma unroll
                    for (int r = 0; r < 4; ++r) o_acc[nb][r] *= ar[r];
            }

            const float negmC = -m_r * EXPC;
#pragma unroll
            for (int nb = 0; nb < 4; ++nb) {
                float p0 = exp2f(fmaf(sc2[nb][0], EXPC, negmC));
                float p1 = exp2f(fmaf(sc2[nb][1], EXPC, negmC));
                float p2 = exp2f(fmaf(sc2[nb][2], EXPC, negmC));
                float p3 = exp2f(fmaf(sc2[nb][3], EXPC, negmC));
                uint2 u;
                u.x = cvtpk(p0, p1);
                u.y = cvtpk(p2, p3);
                *reinterpret_cast<uint2*>(PW + pw[nb]) = u;
            }

            __builtin_amdgcn_s_setprio(1);
#pragma unroll
            for (int kk = 0; kk < 2; ++kk) {
                s16x8 pa = *reinterpret_cast<const s16x8*>(PW + pr[kk]);
                s16x8 bvv[4];
#pragma unroll
                for (int nb = 0; nb < 4; ++nb)
                    bvv[nb] = *reinterpret_cast<const s16x8*>(VB + ko[kk * 4 + nb]);
#pragma unroll
                for (int nb = 0; nb < 4; ++nb)
                    o_acc[nb] = __builtin_amdgcn_mfma_f32_16x16x32_bf16(pa, bvv[nb], o_acc[nb], 0, 0, 0);
                l_acc = __builtin_amdgcn_mfma_f32_16x16x32_bf16(pa, onesb, l_acc, 0, 0, 0);
            }
            __builtin_amdgcn_s_setprio(0);
        };

        stage(0);
        __syncthreads();
        int cur = 0;

#pragma unroll 1
        for (int t = 0; t < qt; ++t) {
            stage(cur ^ 1);
            tile(cur * 8192, false);
            __syncthreads();
            cur ^= 1;
        }
        tile(cur * 8192, true);

        // epilogue: zero-shuffle (l_acc rows == o_acc rows)
        float linv[4];
#pragma unroll
        for (int r = 0; r < 4; ++r) linv[r] = 1.0f / l_acc[r];
#pragma unroll
        for (int nb = 0; nb < 4; ++nb)
#pragma unroll
            for (int r = 0; r < 4; ++r) {
                const int s = q0 + wid * 16 + lhi * 4 + r;
                Ao[((size_t)b * SLEN + s) * DMOD + h * 64 + nb * 16 + l15] =
                    f2bf(o_acc[nb][r] * linv[r]);
            }
        __syncthreads();   // protect buffers before next segment's stage
    }
}

extern "C" void kernel_launch(void* const* d_in, const int* in_sizes, int n_in,
                              void* d_out, int out_size, void* d_ws, size_t ws_size,
                              hipStream_t stream) {
    const float* q  = (const float*)d_in[0];
    const float* k  = (const float*)d_in[1];
    const float* v  = (const float*)d_in[2];
    const float* Wq = (const float*)d_in[4];
    const float* bq = (const float*)d_in[5];
    const float* Wk = (const float*)d_in[6];
    const float* bk = (const float*)d_in[7];
    const float* Wv = (const float*)d_in[8];
    const float* bv = (const float*)d_in[9];
    const float* Wo = (const float*)d_in[10];
    const float* bo = (const float*)d_in[11];

    // ws layout (ushort units): Q, K, V^T, attn-out. Peak 67 MB.
    unsigned short* wsp = (unsigned short*)d_ws;
    unsigned short* qb  = wsp;
    unsigned short* kb  = wsp + 8388608;
    unsigned short* vtb = wsp + 16777216;
    unsigned short* ao  = wsp + 25165824;

    dim3 gb(256);
    gemm_v4<0, false><<<dim3(512), gb, 0, stream>>>(q, Wq, bq, qb);
    gemm_v4<0, false><<<dim3(512), gb, 0, stream>>>(k, Wk, bk, kb);
    gemm_v4<1, false><<<dim3(512), gb, 0, stream>>>(v, Wv, bv, vtb);
    attn_kernel<<<dim3(1024), gb, 0, stream>>>(qb, kb, vtb, ao);
    gemm_v4<2, true><<<dim3(512), gb, 0, stream>>>(ao, Wo, bo, (float*)d_out);
}